// Round 1
// baseline (1115.897 us; speedup 1.0000x reference)
//
#include <hip/hip_runtime.h>

typedef float  floatx4  __attribute__((ext_vector_type(4)));
typedef float  floatx2  __attribute__((ext_vector_type(2)));
typedef __bf16 bf16x8   __attribute__((ext_vector_type(8)));
typedef unsigned short ushort8v __attribute__((ext_vector_type(8)));

constexpr int NB = 64;       // batch
constexpr int NT = 512;      // time
constexpr int DC = 4096, DD = 512, DM = 256, DTOT = 4864;
constexpr int RED = 128;
constexpr int MROWS = NB * NT;  // 32768

__device__ __forceinline__ unsigned short f2bf(float f) {
  unsigned u = __float_as_uint(f);
  unsigned r = u + 0x7FFFu + ((u >> 16) & 1u);   // RNE f32->bf16
  return (unsigned short)(r >> 16);
}

__device__ __forceinline__ ushort8v pack8(floatx4 a, floatx4 b) {
  ushort8v u;
  u[0] = f2bf(a[0]); u[1] = f2bf(a[1]); u[2] = f2bf(a[2]); u[3] = f2bf(a[3]);
  u[4] = f2bf(b[0]); u[5] = f2bf(b[1]); u[6] = f2bf(b[2]); u[7] = f2bf(b[3]);
  return u;
}

// C = A @ W^T + bias.  MODE 0: A = concat(content,distort,motion) [M,4864], W=fc0_w [128,4864]
//                      MODE 1: A = scores [M,128], W = stacked [wih_f;wih_b] [192,128]
// 64-row M tile, full N per block. bf16 MFMA 16x16x32, fp32 acc.
// Pipelined: chunk k+1 is register-prefetched during the MFMA phase of chunk k,
// so HBM latency overlaps compute instead of being barrier-drained per iteration.
// LDS swizzle: 128-wide rows, chunk' = chunk ^ (row&15) -> 16 rows hit 16 distinct
// 16B slots (2-way bank aliasing = free).
template<int MODE>
__global__ __launch_bounds__(256, 2) void gemm_bt(
    const float* __restrict__ A0, const float* __restrict__ A1, const float* __restrict__ A2,
    const float* __restrict__ W0, const float* __restrict__ W1,
    const float* __restrict__ bias0, const float* __restrict__ bias1,
    float* __restrict__ outp)
{
  constexpr int BN   = (MODE == 0) ? 128 : 192;
  constexpr int KTOT = (MODE == 0) ? DTOT : RED;
  constexpr int WNT  = (MODE == 0) ? 2 : 3;       // n-tiles per wave
  constexpr int BK   = 128;                       // k per LDS chunk
  constexpr int ACH  = 64 * (BK / 8) / 256;       // A 8-elem chunks per thread (4)
  constexpr int WCH  = BN * (BK / 8) / 256;       // W chunks per thread (8 / 12)

  __shared__ __align__(16) unsigned short As[64 * BK];
  __shared__ __align__(16) unsigned short Ws[BN * BK];

  const int tid  = threadIdx.x;
  const int lane = tid & 63;
  const int wave = tid >> 6;
  const int m0   = blockIdx.x * 64;

  floatx4 pa[2 * ACH], pw[2 * WCH];

  auto loadA = [&](int k0) {
    #pragma unroll
    for (int c = 0; c < ACH; ++c) {
      const int g   = c * 256 + tid;
      const int row = g >> 4;
      const int kk  = (g & 15) * 8;
      const int m   = m0 + row;
      const float* src;
      if (MODE == 0) {
        const int k = k0 + kk;   // 128-chunks never straddle concat boundaries (all %128==0)
        if (k < DC)           src = A0 + (size_t)m * DC + k;
        else if (k < DC + DD) src = A1 + (size_t)m * DD + (k - DC);
        else                  src = A2 + (size_t)m * DM + (k - DC - DD);
      } else {
        src = A0 + (size_t)m * RED + (k0 + kk);
      }
      pa[2 * c]     = *(const floatx4*)(src);
      pa[2 * c + 1] = *(const floatx4*)(src + 4);
    }
  };
  auto loadW = [&](int k0) {
    #pragma unroll
    for (int c = 0; c < WCH; ++c) {
      const int g   = c * 256 + tid;
      const int row = g >> 4;
      const int kk  = (g & 15) * 8;
      const float* src;
      if (MODE == 0) {
        src = W0 + (size_t)row * DTOT + (k0 + kk);
      } else {
        src = (row < 96) ? (W0 + (size_t)row * RED + (k0 + kk))
                         : (W1 + (size_t)(row - 96) * RED + (k0 + kk));
      }
      pw[2 * c]     = *(const floatx4*)(src);
      pw[2 * c + 1] = *(const floatx4*)(src + 4);
    }
  };
  auto storeA = [&]() {
    #pragma unroll
    for (int c = 0; c < ACH; ++c) {
      const int g   = c * 256 + tid;
      const int row = g >> 4;
      const int kk  = (g & 15) * 8;
      *(ushort8v*)&As[row * BK + (kk ^ ((row & 15) * 8))] = pack8(pa[2 * c], pa[2 * c + 1]);
    }
  };
  auto storeW = [&]() {
    #pragma unroll
    for (int c = 0; c < WCH; ++c) {
      const int g   = c * 256 + tid;
      const int row = g >> 4;
      const int kk  = (g & 15) * 8;
      *(ushort8v*)&Ws[row * BK + (kk ^ ((row & 15) * 8))] = pack8(pw[2 * c], pw[2 * c + 1]);
    }
  };

  floatx4 acc[4][WNT];
  #pragma unroll
  for (int mt = 0; mt < 4; ++mt)
    #pragma unroll
    for (int nt = 0; nt < WNT; ++nt)
      acc[mt][nt] = (floatx4){0.f, 0.f, 0.f, 0.f};

  const int lrow = lane & 15;
  const int lko  = (lane >> 4) * 8;

  loadA(0); loadW(0);

  for (int k0 = 0; k0 < KTOT; k0 += BK) {
    storeA(); storeW();
    __syncthreads();
    if (k0 + BK < KTOT) { loadA(k0 + BK); loadW(k0 + BK); }  // overlaps MFMA phase below
    #pragma unroll
    for (int kk = 0; kk < BK; kk += 32) {
      bf16x8 af[4];
      #pragma unroll
      for (int mt = 0; mt < 4; ++mt) {
        const int row = mt * 16 + lrow;
        af[mt] = __builtin_bit_cast(bf16x8,
            *(const ushort8v*)&As[row * BK + ((kk + lko) ^ ((row & 15) * 8))]);
      }
      #pragma unroll
      for (int nt = 0; nt < WNT; ++nt) {
        const int wrow = (wave * WNT + nt) * 16 + lrow;
        bf16x8 wf = __builtin_bit_cast(bf16x8,
            *(const ushort8v*)&Ws[wrow * BK + ((kk + lko) ^ ((wrow & 15) * 8))]);
        #pragma unroll
        for (int mt = 0; mt < 4; ++mt)
          acc[mt][nt] = __builtin_amdgcn_mfma_f32_16x16x32_bf16(af[mt], wf, acc[mt][nt], 0, 0, 0);
      }
    }
    __syncthreads();
  }

  // ---- epilogue: C/D layout col=lane&15, row=(lane>>4)*4+r ----
  #pragma unroll
  for (int nt = 0; nt < WNT; ++nt) {
    const int n = (wave * WNT + nt) * 16 + lrow;
    const float bv = (MODE == 0) ? bias0[n]
                                 : ((n < 96) ? bias0[n] : bias1[n - 96]);
    #pragma unroll
    for (int mt = 0; mt < 4; ++mt) {
      const int mr = m0 + mt * 16 + (lane >> 4) * 4;
      #pragma unroll
      for (int r = 0; r < 4; ++r)
        outp[(size_t)(mr + r) * BN + n] = acc[mt][nt][r] + bv;
    }
  }
}

// One block (=1 wave) per (batch, dir).
// 64-lane split dot: lane l owns h-half (l>>5) of hidden row (l&31) -> 48 FMAs/step
// issued as 24 v_pk_fma_f32 (issue ~48cy vs 192cy for the 32-lane version); halves
// are combined with one __shfl_xor(.,32) per gate.  xg is software-prefetched 2 steps
// ahead so its L2/L3 latency (~300-600cy) never sits on the recurrence chain.
// tanh computed as 2/(1+exp(-2x))-1 (~5 ops vs tanhf's ~25; err ~1e-7 << bf16-GEMM err).
// q = outputs . q_w is fused in (wave reduce per step, off the critical path), so the
// old outfb buffer (16 MB RW) and q_kernel disappear; only the 2 final hidden vectors
// are emitted for the memory-MLP.
__global__ __launch_bounds__(64) void gru_kernel(
    const float* __restrict__ xg,
    const float* __restrict__ whh_f, const float* __restrict__ whh_b,
    const float* __restrict__ bhh_f, const float* __restrict__ bhh_b,
    const float* __restrict__ q_w,
    const int* __restrict__ inputLength,
    float* __restrict__ qpart,      // [2][NB*NT]  (dir-major)
    float* __restrict__ hid)        // [NB][64]  = [lastHidForward | lastHidBackward]
{
  const int b    = blockIdx.x >> 1;
  const int dir  = blockIdx.x & 1;
  const int l    = threadIdx.x;
  const int half = l >> 5;          // which 16-wide h slice this lane dots
  const int row  = l & 31;          // which hidden row (gate output) this lane owns
  const int vlen = inputLength[b] - 9;

  const float* whh = dir ? whh_b : whh_f;
  const float* bhh = dir ? bhh_b : bhh_f;

  __shared__ __align__(16) float hsh[32];

  // per-lane weights: 8 packed f32 pairs per gate over h[16*half .. 16*half+15]
  floatx2 wr[8], wz[8], wn[8];
  #pragma unroll
  for (int j = 0; j < 8; ++j) {
    const int c = 16 * half + 2 * j;
    wr[j] = *(const floatx2*)&whh[(size_t)row        * 32 + c];
    wz[j] = *(const floatx2*)&whh[(size_t)(32 + row) * 32 + c];
    wn[j] = *(const floatx2*)&whh[(size_t)(64 + row) * 32 + c];
  }
  const float br = bhh[row], bz = bhh[32 + row], bn = bhh[64 + row];
  const float qw = q_w[dir * 32 + row];

  if (l < 32) hsh[l] = 0.f;
  __syncthreads();

  // xg prefetch pipeline, distance 2 (cur / nxt registers, renamed each iter)
  auto xaddr = [&](int tt) {
    const int time = dir ? (vlen - 1 - tt) : tt;
    return xg + (size_t)(b * NT + time) * 192 + dir * 96;
  };
  float c_r = 0.f, c_z = 0.f, c_n = 0.f, n_r = 0.f, n_z = 0.f, n_n = 0.f;
  if (l < 32) {
    const float* x0 = xaddr(0);
    c_r = x0[l]; c_z = x0[32 + l]; c_n = x0[64 + l];
    if (vlen > 1) {
      const float* x1 = xaddr(1);
      n_r = x1[l]; n_z = x1[32 + l]; n_n = x1[64 + l];
    }
  }

  float* qout = qpart + (size_t)dir * (NB * NT) + (size_t)b * NT;

  float hl = 0.f;                   // this lane's own h[row] (lanes <32)
  for (int t = 0; t < vlen; ++t) {
    const int time = dir ? (vlen - 1 - t) : t;

    // issue load for t+2; consumed two iterations from now
    float f_r = 0.f, f_z = 0.f, f_n = 0.f;
    if (t + 2 < vlen && l < 32) {
      const float* x2 = xaddr(t + 2);
      f_r = x2[l]; f_z = x2[32 + l]; f_n = x2[64 + l];
    }

    // broadcast-read this lane's h slice (lanes 0-31 one addr, 32-63 another: conflict-free)
    float h[16];
    #pragma unroll
    for (int i = 0; i < 4; ++i)
      *(floatx4*)&h[4 * i] = *(const floatx4*)&hsh[16 * half + 4 * i];
    const floatx2* h2 = (const floatx2*)h;

    floatx2 ar = {0.f, 0.f}, az = {0.f, 0.f}, an = {0.f, 0.f};
    floatx2 ar1 = {0.f, 0.f}, az1 = {0.f, 0.f}, an1 = {0.f, 0.f};
    #pragma unroll
    for (int j = 0; j < 4; ++j) {
      ar  += wr[j]     * h2[j];     ar1 += wr[4 + j] * h2[4 + j];
      az  += wz[j]     * h2[j];     az1 += wz[4 + j] * h2[4 + j];
      an  += wn[j]     * h2[j];     an1 += wn[4 + j] * h2[4 + j];
    }
    float pr = ar[0] + ar[1] + ar1[0] + ar1[1];
    float pz = az[0] + az[1] + az1[0] + az1[1];
    float pn = an[0] + an[1] + an1[0] + an1[1];
    pr += __shfl_xor(pr, 32);       // combine the two h-halves
    pz += __shfl_xor(pz, 32);
    pn += __shfl_xor(pn, 32);

    float hn = hl;
    if (l < 32) {
      const float r = 1.f / (1.f + __expf(-(c_r + pr + br)));
      const float z = 1.f / (1.f + __expf(-(c_z + pz + bz)));
      const float e = __expf(-2.f * (c_n + r * (pn + bn)));
      const float n = 2.f / (1.f + e) - 1.f;            // tanh
      hn = (1.f - z) * n + z * hl;
      hl = hn;
      hsh[l] = hn;
    }

    // q partial for this (dir,time): sum over lanes<32 of hn*qw  (off critical path)
    float qp = (l < 32) ? hn * qw : 0.f;
    #pragma unroll
    for (int off = 16; off > 0; off >>= 1)
      qp += __shfl_xor(qp, off);
    if (l == 0) qout[time] = qp;

    if (t == vlen - 1 && l < 32) hid[b * 64 + dir * 32 + l] = hn;

    c_r = n_r; c_z = n_z; c_n = n_n;
    n_r = f_r; n_z = f_z; n_n = f_n;
  }
}

// Per-batch: memory-MLP -> argmax tau; TP score for that tau only; mean over valid frames.
__global__ __launch_bounds__(64) void final_kernel(
    const float* __restrict__ qf, const float* __restrict__ qb,
    const float* __restrict__ hid,
    const float* __restrict__ q_b,
    const int* __restrict__ inputLength,
    const float* __restrict__ m1w, const float* __restrict__ m1b,
    const float* __restrict__ m2w, const float* __restrict__ m2b,
    float* __restrict__ fin)
{
  const int b = blockIdx.x;
  const int tid = threadIdx.x;
  const int vlen = inputLength[b] - 9;
  const float qb0 = q_b[0];

  __shared__ float qs[NT];
  __shared__ float es[NT];
  __shared__ float h1[32];
  __shared__ int tau_s;

  for (int t = tid; t < vlen; t += 64) {
    const float v = qf[b * NT + t] + qb[b * NT + t] + qb0;
    qs[t] = v;
    es[t] = expf(-v);
  }

  if (tid < 32) {
    const float* hf = hid + b * 64;        // lastHidForward
    const float* hb = hid + b * 64 + 32;   // lastHidBackward
    float a = m1b[tid];
    #pragma unroll
    for (int j = 0; j < 32; ++j) a += m1w[tid * 64 + j] * hf[j];
    #pragma unroll
    for (int j = 0; j < 32; ++j) a += m1w[tid * 64 + 32 + j] * hb[j];
    h1[tid] = fmaxf(a, 0.f);
  }
  __syncthreads();
  if (tid == 0) {
    float best = -3.4e38f; int bi = 0;
    for (int i = 0; i < 5; ++i) {
      float lg = m2b[i];
      for (int j = 0; j < 32; ++j) lg += m2w[i * 32 + j] * h1[j];
      if (lg > best) { best = lg; bi = i; }   // softmax is monotone; first-max like jnp.argmax
    }
    tau_s = 8 + 2 * bi;
  }
  __syncthreads();
  const int tau = tau_s;

  float partial = 0.f;
  for (int t = tid; t < vlen; t += 64) {
    float msum = 0.f, nsum = 0.f;
    const int kmax = (tau < vlen - t) ? tau : (vlen - t);   // w=0 beyond vlen
    for (int k = 0; k < kmax; ++k) { msum += qs[t + k] * es[t + k]; nsum += es[t + k]; }
    const float ratio = (nsum > 0.f) ? (msum / nsum) : 0.f;
    float l = 3.4e38f;
    const int kb = (tau <= t + 1) ? tau : (t + 1);          // inf-pad for t-k<0
    for (int k = 0; k < kb; ++k) l = fminf(l, qs[t - k]);
    partial += 0.5f * ratio + 0.5f * l;
  }
  #pragma unroll
  for (int off = 32; off > 0; off >>= 1)
    partial += __shfl_down(partial, off);
  if (tid == 0) fin[b] = partial / (float)vlen;
}

extern "C" void kernel_launch(void* const* d_in, const int* in_sizes, int n_in,
                              void* d_out, int out_size, void* d_ws, size_t ws_size,
                              hipStream_t stream)
{
  const float* motion  = (const float*)d_in[0];
  const float* content = (const float*)d_in[1];
  const float* distort = (const float*)d_in[2];
  const int*   ilen    = (const int*)d_in[3];
  const float* fc0_w = (const float*)d_in[4];
  const float* fc0_b = (const float*)d_in[5];
  const float* wih_f = (const float*)d_in[6];
  const float* whh_f = (const float*)d_in[7];
  const float* bih_f = (const float*)d_in[8];
  const float* bhh_f = (const float*)d_in[9];
  const float* wih_b = (const float*)d_in[10];
  const float* whh_b = (const float*)d_in[11];
  const float* bih_b = (const float*)d_in[12];
  const float* bhh_b = (const float*)d_in[13];
  const float* q_w  = (const float*)d_in[14];
  const float* q_b  = (const float*)d_in[15];
  const float* m1w  = (const float*)d_in[16];
  const float* m1b  = (const float*)d_in[17];
  const float* m2w  = (const float*)d_in[18];
  const float* m2b  = (const float*)d_in[19];

  // workspace layout (~40.3 MB)
  char* ws = (char*)d_ws;
  float* scores = (float*)(ws);                                            // 16 MB [32768,128]
  float* xg     = (float*)(ws + (size_t)MROWS * RED * 4);                  // 24 MB [32768,192]
  float* qpart  = (float*)(ws + (size_t)MROWS * (RED + 192) * 4);          // 256 KB [2][32768]
  float* hid    = (float*)(ws + (size_t)MROWS * (RED + 192) * 4
                              + (size_t)2 * MROWS * 4);                    // 16 KB [64][64]

  gemm_bt<0><<<dim3(MROWS / 64), dim3(256), 0, stream>>>(
      content, distort, motion, fc0_w, nullptr, fc0_b, nullptr, scores);
  gemm_bt<1><<<dim3(MROWS / 64), dim3(256), 0, stream>>>(
      scores, nullptr, nullptr, wih_f, wih_b, bih_f, bih_b, xg);
  gru_kernel<<<dim3(NB * 2), dim3(64), 0, stream>>>(
      xg, whh_f, whh_b, bhh_f, bhh_b, q_w, ilen, qpart, hid);
  final_kernel<<<dim3(NB), dim3(64), 0, stream>>>(
      qpart, qpart + (size_t)NB * NT, hid, q_b, ilen, m1w, m1b, m2w, m2b, (float*)d_out);
}

// Round 2
// 1075.335 us; speedup vs baseline: 1.0377x; 1.0377x over previous
//
#include <hip/hip_runtime.h>

typedef float  floatx4  __attribute__((ext_vector_type(4)));
typedef float  floatx2  __attribute__((ext_vector_type(2)));
typedef __bf16 bf16x8   __attribute__((ext_vector_type(8)));
typedef unsigned short ushort8v __attribute__((ext_vector_type(8)));

constexpr int NB = 64;       // batch
constexpr int NT = 512;      // time
constexpr int DC = 4096, DD = 512, DM = 256, DTOT = 4864;
constexpr int RED = 128;
constexpr int MROWS = NB * NT;  // 32768

__device__ __forceinline__ unsigned short f2bf(float f) {
  unsigned u = __float_as_uint(f);
  unsigned r = u + 0x7FFFu + ((u >> 16) & 1u);   // RNE f32->bf16
  return (unsigned short)(r >> 16);
}

__device__ __forceinline__ ushort8v pack8(floatx4 a, floatx4 b) {
  ushort8v u;
  u[0] = f2bf(a[0]); u[1] = f2bf(a[1]); u[2] = f2bf(a[2]); u[3] = f2bf(a[3]);
  u[4] = f2bf(b[0]); u[5] = f2bf(b[1]); u[6] = f2bf(b[2]); u[7] = f2bf(b[3]);
  return u;
}

// Fused: phase 1  S = concat(content,distort,motion) @ fc0_w^T + fc0_b   (64x128 tile)
//        phase 2  xg = S @ [wih_f;wih_b]^T + [bih_f;bih_b]               (64x192 tile)
// Phase 1 is the proven MODE-0 pipeline (register prefetch of chunk k+1 during MFMA of
// chunk k, swizzled LDS).  Phase 2 reuses the A-LDS for the bf16-rounded score tile
// (identical rounding point to the old scores->gemm1 path) and one 48KB wih stage,
// eliminating the separate gemm1 dispatch and 32 MB of scores write+read traffic.
__global__ __launch_bounds__(256, 2) void gemm_fused(
    const float* __restrict__ A0, const float* __restrict__ A1, const float* __restrict__ A2,
    const float* __restrict__ fc0w, const float* __restrict__ fc0b,
    const float* __restrict__ wihf, const float* __restrict__ wihb,
    const float* __restrict__ bihf, const float* __restrict__ bihb,
    float* __restrict__ xg)
{
  constexpr int BK  = 128;
  constexpr int ACH = 4;   // 64*16/256
  constexpr int WCH = 8;   // 128*16/256

  __shared__ __align__(16) unsigned short As[64 * BK];     // 16 KB; S-tile in phase 2
  __shared__ __align__(16) unsigned short Ws[192 * BK];    // 48 KB; phase 1 uses 32 KB

  const int tid  = threadIdx.x;
  const int lane = tid & 63;
  const int wave = tid >> 6;
  const int m0   = blockIdx.x * 64;

  floatx4 pa[2 * ACH], pw[2 * WCH];

  auto loadA = [&](int k0) {
    #pragma unroll
    for (int c = 0; c < ACH; ++c) {
      const int g   = c * 256 + tid;
      const int row = g >> 4;
      const int kk  = (g & 15) * 8;
      const int m   = m0 + row;
      const int k   = k0 + kk;   // 128-chunks never straddle concat boundaries
      const float* src;
      if (k < DC)           src = A0 + (size_t)m * DC + k;
      else if (k < DC + DD) src = A1 + (size_t)m * DD + (k - DC);
      else                  src = A2 + (size_t)m * DM + (k - DC - DD);
      pa[2 * c]     = *(const floatx4*)(src);
      pa[2 * c + 1] = *(const floatx4*)(src + 4);
    }
  };
  auto loadW = [&](int k0) {
    #pragma unroll
    for (int c = 0; c < WCH; ++c) {
      const int g   = c * 256 + tid;
      const int row = g >> 4;
      const int kk  = (g & 15) * 8;
      const float* src = fc0w + (size_t)row * DTOT + (k0 + kk);
      pw[2 * c]     = *(const floatx4*)(src);
      pw[2 * c + 1] = *(const floatx4*)(src + 4);
    }
  };
  auto storeA = [&]() {
    #pragma unroll
    for (int c = 0; c < ACH; ++c) {
      const int g   = c * 256 + tid;
      const int row = g >> 4;
      const int kk  = (g & 15) * 8;
      *(ushort8v*)&As[row * BK + (kk ^ ((row & 15) * 8))] = pack8(pa[2 * c], pa[2 * c + 1]);
    }
  };
  auto storeW = [&]() {
    #pragma unroll
    for (int c = 0; c < WCH; ++c) {
      const int g   = c * 256 + tid;
      const int row = g >> 4;
      const int kk  = (g & 15) * 8;
      *(ushort8v*)&Ws[row * BK + (kk ^ ((row & 15) * 8))] = pack8(pw[2 * c], pw[2 * c + 1]);
    }
  };

  floatx4 acc[4][2];
  #pragma unroll
  for (int mt = 0; mt < 4; ++mt)
    #pragma unroll
    for (int nt = 0; nt < 2; ++nt)
      acc[mt][nt] = (floatx4){0.f, 0.f, 0.f, 0.f};

  const int lrow = lane & 15;
  const int lko  = (lane >> 4) * 8;

  loadA(0); loadW(0);

  for (int k0 = 0; k0 < DTOT; k0 += BK) {
    storeA(); storeW();
    __syncthreads();
    if (k0 + BK < DTOT) { loadA(k0 + BK); loadW(k0 + BK); }  // overlaps MFMA phase
    #pragma unroll
    for (int kk = 0; kk < BK; kk += 32) {
      bf16x8 af[4];
      #pragma unroll
      for (int mt = 0; mt < 4; ++mt) {
        const int row = mt * 16 + lrow;
        af[mt] = __builtin_bit_cast(bf16x8,
            *(const ushort8v*)&As[row * BK + ((kk + lko) ^ ((row & 15) * 8))]);
      }
      #pragma unroll
      for (int nt = 0; nt < 2; ++nt) {
        const int wrow = (wave * 2 + nt) * 16 + lrow;
        bf16x8 wf = __builtin_bit_cast(bf16x8,
            *(const ushort8v*)&Ws[wrow * BK + ((kk + lko) ^ ((wrow & 15) * 8))]);
        #pragma unroll
        for (int mt = 0; mt < 4; ++mt)
          acc[mt][nt] = __builtin_amdgcn_mfma_f32_16x16x32_bf16(af[mt], wf, acc[mt][nt], 0, 0, 0);
      }
    }
    __syncthreads();
  }

  // ---- phase 2: S tile (bf16, same rounding as old scores path) into As ----
  #pragma unroll
  for (int nt = 0; nt < 2; ++nt) {
    const int n  = (wave * 2 + nt) * 16 + lrow;
    const float bv = fc0b[n];
    #pragma unroll
    for (int mt = 0; mt < 4; ++mt) {
      const int rb = mt * 16 + (lane >> 4) * 4;
      #pragma unroll
      for (int r = 0; r < 4; ++r) {
        const int row = rb + r;
        As[row * BK + (n ^ ((row & 15) * 8))] = f2bf(acc[mt][nt][r] + bv);
      }
    }
  }
  // stage [wih_f;wih_b] (192x128) as bf16
  #pragma unroll
  for (int c = 0; c < 12; ++c) {
    const int g   = c * 256 + tid;
    const int row = g >> 4;          // 0..191
    const int kk  = (g & 15) * 8;
    const float* src = (row < 96) ? (wihf + (size_t)row * RED + kk)
                                  : (wihb + (size_t)(row - 96) * RED + kk);
    floatx4 u0 = *(const floatx4*)src, u1 = *(const floatx4*)(src + 4);
    *(ushort8v*)&Ws[row * BK + (kk ^ ((row & 15) * 8))] = pack8(u0, u1);
  }
  __syncthreads();

  floatx4 acc2[4][3];
  #pragma unroll
  for (int mt = 0; mt < 4; ++mt)
    #pragma unroll
    for (int nt = 0; nt < 3; ++nt)
      acc2[mt][nt] = (floatx4){0.f, 0.f, 0.f, 0.f};

  #pragma unroll
  for (int kk = 0; kk < BK; kk += 32) {
    bf16x8 af[4];
    #pragma unroll
    for (int mt = 0; mt < 4; ++mt) {
      const int row = mt * 16 + lrow;
      af[mt] = __builtin_bit_cast(bf16x8,
          *(const ushort8v*)&As[row * BK + ((kk + lko) ^ ((row & 15) * 8))]);
    }
    #pragma unroll
    for (int nt = 0; nt < 3; ++nt) {
      const int wrow = (wave * 3 + nt) * 16 + lrow;
      bf16x8 wf = __builtin_bit_cast(bf16x8,
          *(const ushort8v*)&Ws[wrow * BK + ((kk + lko) ^ ((wrow & 15) * 8))]);
      #pragma unroll
      for (int mt = 0; mt < 4; ++mt)
        acc2[mt][nt] = __builtin_amdgcn_mfma_f32_16x16x32_bf16(af[mt], wf, acc2[mt][nt], 0, 0, 0);
    }
  }

  // ---- epilogue: xg [M,192] ----
  #pragma unroll
  for (int nt = 0; nt < 3; ++nt) {
    const int n  = (wave * 3 + nt) * 16 + lrow;
    const float bv = (n < 96) ? bihf[n] : bihb[n - 96];
    #pragma unroll
    for (int mt = 0; mt < 4; ++mt) {
      const int mr = m0 + mt * 16 + (lane >> 4) * 4;
      #pragma unroll
      for (int r = 0; r < 4; ++r)
        xg[(size_t)(mr + r) * 192 + n] = acc2[mt][nt][r] + bv;
    }
  }
}

// One block (=1 wave) per (batch, dir).  Lane l<32 owns the FULL weight row l of each
// gate (16 packed f32 pairs per gate -> 48 v_pk_fma_f32/step, no cross-lane combine).
// The recurrence loop has ZERO cross-lane/shuffle ops and ZERO global stores: h_t is
// written to an LDS history buffer hbuf[t] (36-float stride: 16B-aligned, banks spread
// (4t+j)%32), and the q projection is a separate strided pass over hbuf after the loop
// (off the recurrence entirely).  xg is register-prefetched 2 steps ahead.
__global__ __launch_bounds__(64) void gru_kernel(
    const float* __restrict__ xg,
    const float* __restrict__ whh_f, const float* __restrict__ whh_b,
    const float* __restrict__ bhh_f, const float* __restrict__ bhh_b,
    const float* __restrict__ q_w,
    const int* __restrict__ inputLength,
    float* __restrict__ qpart,      // [2][NB*NT]  (dir-major)
    float* __restrict__ hid)        // [NB][64]  = [lastHidForward | lastHidBackward]
{
  constexpr int HP = 36;            // padded row stride (floats)
  const int b    = blockIdx.x >> 1;
  const int dir  = blockIdx.x & 1;
  const int l    = threadIdx.x;
  const int row  = l & 31;
  const int vlen = inputLength[b] - 9;

  const float* whh = dir ? whh_b : whh_f;
  const float* bhh = dir ? bhh_b : bhh_f;

  __shared__ __align__(16) float hbuf[NT * HP];   // 72 KB history

  floatx2 wr[16], wz[16], wn[16];
  float br = 0.f, bz = 0.f, bn = 0.f;
  if (l < 32) {
    #pragma unroll
    for (int j = 0; j < 16; ++j) {
      wr[j] = *(const floatx2*)&whh[(size_t)row        * 32 + 2 * j];
      wz[j] = *(const floatx2*)&whh[(size_t)(32 + row) * 32 + 2 * j];
      wn[j] = *(const floatx2*)&whh[(size_t)(64 + row) * 32 + 2 * j];
    }
    br = bhh[row]; bz = bhh[32 + row]; bn = bhh[64 + row];
  } else {
    #pragma unroll
    for (int j = 0; j < 16; ++j) {
      wr[j] = (floatx2){0.f, 0.f}; wz[j] = (floatx2){0.f, 0.f}; wn[j] = (floatx2){0.f, 0.f};
    }
  }

  auto xaddr = [&](int tt) {
    const int time = dir ? (vlen - 1 - tt) : tt;
    return xg + (size_t)(b * NT + time) * 192 + dir * 96;
  };
  float c_r = 0.f, c_z = 0.f, c_n = 0.f, n_r = 0.f, n_z = 0.f, n_n = 0.f;
  if (l < 32) {
    const float* x0 = xaddr(0);
    c_r = x0[l]; c_z = x0[32 + l]; c_n = x0[64 + l];
    const float* x1 = xaddr(1);    // vlen >= 191, always valid
    n_r = x1[l]; n_z = x1[32 + l]; n_n = x1[64 + l];
  }

  float hl = 0.f;
  for (int t = 0; t < vlen; ++t) {
    const int time = dir ? (vlen - 1 - t) : t;

    // issue load for t+2; consumed two iterations from now
    float f_r = 0.f, f_z = 0.f, f_n = 0.f;
    if (t + 2 < vlen && l < 32) {
      const float* x2 = xaddr(t + 2);
      f_r = x2[l]; f_z = x2[32 + l]; f_n = x2[64 + l];
    }

    float h[32];
    if (t == 0) {
      #pragma unroll
      for (int j = 0; j < 32; ++j) h[j] = 0.f;
    } else {
      const int pt = dir ? (time + 1) : (time - 1);
      const float* hp = &hbuf[pt * HP];
      #pragma unroll
      for (int i = 0; i < 8; ++i)
        *(floatx4*)&h[4 * i] = *(const floatx4*)&hp[4 * i];   // broadcast reads
    }
    const floatx2* h2 = (const floatx2*)h;

    floatx2 ar0 = {0.f, 0.f}, az0 = {0.f, 0.f}, an0 = {0.f, 0.f};
    floatx2 ar1 = {0.f, 0.f}, az1 = {0.f, 0.f}, an1 = {0.f, 0.f};
    #pragma unroll
    for (int j = 0; j < 8; ++j) {
      ar0 += wr[j] * h2[j];     ar1 += wr[8 + j] * h2[8 + j];
      az0 += wz[j] * h2[j];     az1 += wz[8 + j] * h2[8 + j];
      an0 += wn[j] * h2[j];     an1 += wn[8 + j] * h2[8 + j];
    }
    const float pr = ar0[0] + ar0[1] + ar1[0] + ar1[1];
    const float pz = az0[0] + az0[1] + az1[0] + az1[1];
    const float pn = an0[0] + an0[1] + an1[0] + an1[1];

    if (l < 32) {
      const float r = 1.f / (1.f + __expf(-(c_r + pr + br)));
      const float z = 1.f / (1.f + __expf(-(c_z + pz + bz)));
      const float e = __expf(-2.f * (c_n + r * (pn + bn)));
      const float n = 2.f / (1.f + e) - 1.f;            // tanh
      const float hn = (1.f - z) * n + z * hl;
      hl = hn;
      hbuf[time * HP + l] = hn;
      if (t == vlen - 1) hid[b * 64 + dir * 32 + l] = hn;
    }

    c_r = n_r; c_z = n_z; c_n = n_n;
    n_r = f_r; n_z = f_z; n_n = f_n;
  }

  // q pass: q[dir][b][t] = hbuf[t] . q_w[dir*32 .. dir*32+31]  (single wave: program
  // order + lgkmcnt ordering makes the loop's LDS writes visible, no barrier needed)
  float qwv[32];
  #pragma unroll
  for (int i = 0; i < 8; ++i)
    *(floatx4*)&qwv[4 * i] = *(const floatx4*)&q_w[dir * 32 + 4 * i];
  float* qout = qpart + (size_t)dir * (NB * NT) + (size_t)b * NT;
  for (int t = l; t < vlen; t += 64) {
    const float* hr = &hbuf[t * HP];
    float a0 = 0.f, a1 = 0.f;
    #pragma unroll
    for (int j = 0; j < 16; ++j) { a0 += hr[j] * qwv[j]; a1 += hr[16 + j] * qwv[16 + j]; }
    qout[t] = a0 + a1;
  }
}

// Per-batch: memory-MLP -> argmax tau; TP score for that tau only; mean over valid frames.
__global__ __launch_bounds__(64) void final_kernel(
    const float* __restrict__ qf, const float* __restrict__ qb,
    const float* __restrict__ hid,
    const float* __restrict__ q_b,
    const int* __restrict__ inputLength,
    const float* __restrict__ m1w, const float* __restrict__ m1b,
    const float* __restrict__ m2w, const float* __restrict__ m2b,
    float* __restrict__ fin)
{
  const int b = blockIdx.x;
  const int tid = threadIdx.x;
  const int vlen = inputLength[b] - 9;
  const float qb0 = q_b[0];

  __shared__ float qs[NT];
  __shared__ float es[NT];
  __shared__ float h1[32];
  __shared__ int tau_s;

  for (int t = tid; t < vlen; t += 64) {
    const float v = qf[b * NT + t] + qb[b * NT + t] + qb0;
    qs[t] = v;
    es[t] = expf(-v);
  }

  if (tid < 32) {
    const float* hf = hid + b * 64;        // lastHidForward
    const float* hb = hid + b * 64 + 32;   // lastHidBackward
    float a = m1b[tid];
    #pragma unroll
    for (int j = 0; j < 32; ++j) a += m1w[tid * 64 + j] * hf[j];
    #pragma unroll
    for (int j = 0; j < 32; ++j) a += m1w[tid * 64 + 32 + j] * hb[j];
    h1[tid] = fmaxf(a, 0.f);
  }
  __syncthreads();
  if (tid == 0) {
    float best = -3.4e38f; int bi = 0;
    for (int i = 0; i < 5; ++i) {
      float lg = m2b[i];
      for (int j = 0; j < 32; ++j) lg += m2w[i * 32 + j] * h1[j];
      if (lg > best) { best = lg; bi = i; }   // softmax is monotone; first-max like jnp.argmax
    }
    tau_s = 8 + 2 * bi;
  }
  __syncthreads();
  const int tau = tau_s;

  float partial = 0.f;
  for (int t = tid; t < vlen; t += 64) {
    float msum = 0.f, nsum = 0.f;
    const int kmax = (tau < vlen - t) ? tau : (vlen - t);   // w=0 beyond vlen
    for (int k = 0; k < kmax; ++k) { msum += qs[t + k] * es[t + k]; nsum += es[t + k]; }
    const float ratio = (nsum > 0.f) ? (msum / nsum) : 0.f;
    float l = 3.4e38f;
    const int kb = (tau <= t + 1) ? tau : (t + 1);          // inf-pad for t-k<0
    for (int k = 0; k < kb; ++k) l = fminf(l, qs[t - k]);
    partial += 0.5f * ratio + 0.5f * l;
  }
  #pragma unroll
  for (int off = 32; off > 0; off >>= 1)
    partial += __shfl_down(partial, off);
  if (tid == 0) fin[b] = partial / (float)vlen;
}

extern "C" void kernel_launch(void* const* d_in, const int* in_sizes, int n_in,
                              void* d_out, int out_size, void* d_ws, size_t ws_size,
                              hipStream_t stream)
{
  const float* motion  = (const float*)d_in[0];
  const float* content = (const float*)d_in[1];
  const float* distort = (const float*)d_in[2];
  const int*   ilen    = (const int*)d_in[3];
  const float* fc0_w = (const float*)d_in[4];
  const float* fc0_b = (const float*)d_in[5];
  const float* wih_f = (const float*)d_in[6];
  const float* whh_f = (const float*)d_in[7];
  const float* bih_f = (const float*)d_in[8];
  const float* bhh_f = (const float*)d_in[9];
  const float* wih_b = (const float*)d_in[10];
  const float* whh_b = (const float*)d_in[11];
  const float* bih_b = (const float*)d_in[12];
  const float* bhh_b = (const float*)d_in[13];
  const float* q_w  = (const float*)d_in[14];
  const float* q_b  = (const float*)d_in[15];
  const float* m1w  = (const float*)d_in[16];
  const float* m1b  = (const float*)d_in[17];
  const float* m2w  = (const float*)d_in[18];
  const float* m2b  = (const float*)d_in[19];

  // workspace layout (~24.3 MB)
  char* ws = (char*)d_ws;
  float* xg    = (float*)(ws);                                             // 24 MB [32768,192]
  float* qpart = (float*)(ws + (size_t)MROWS * 192 * 4);                   // 256 KB [2][32768]
  float* hid   = (float*)(ws + (size_t)MROWS * 192 * 4 + (size_t)2 * MROWS * 4); // 16 KB

  gemm_fused<<<dim3(MROWS / 64), dim3(256), 0, stream>>>(
      content, distort, motion, fc0_w, fc0_b, wih_f, wih_b, bih_f, bih_b, xg);
  gru_kernel<<<dim3(NB * 2), dim3(64), 0, stream>>>(
      xg, whh_f, whh_b, bhh_f, bhh_b, q_w, ilen, qpart, hid);
  final_kernel<<<dim3(NB), dim3(64), 0, stream>>>(
      qpart, qpart + (size_t)NB * NT, hid, q_b, ilen, m1w, m1b, m2w, m2b, (float*)d_out);
}